// Round 11
// baseline (1746.369 us; speedup 1.0000x reference)
//
#include <hip/hip_runtime.h>

// Seq2Seq LSTM (B=1024, T_IN=168, F_IN=8, H=256, T_OUT=96) on gfx950.
// Round 11: round-10 kernel with the two vector-load compile fixes
// (xs[l15] -> *(const f16x8*)&xs[l15][0]).
//   Theory (from r8/r9): at 2 waves/SIMD there is no TLP to hide ds_read
//   (~120cy) / L2 (~200cy) latency. This kernel runs 1024 threads = 16
//   waves = 4 waves/SIMD (2x latency hiding), and each wave owns 16
//   h-units -> nt == gate index, so the LSTM activation is fully
//   lane-local (no cross-lane gate exchange).
//   - weights/wave: kt0-4 VGPR (20 frags, 80 regs) | kt5 streamed (4 loads)
//     | kt6-7 LDS 128KB | kt8 packed-LDS 16KB
//   - A tile 16x256 f16 single-buffer, 3-bit XOR swizzle (l15&7)
//   - r3's proven 2-barrier step, xs staging, decoder xs-feedback + serial
//     tid<16 fc reduce
// 64 blocks x 1024 threads; wave wv owns h-units [wv*16, +16).

typedef _Float16 f16x8 __attribute__((ext_vector_type(8)));
typedef float f32x4 __attribute__((ext_vector_type(4)));

#define WPW  18432          // packed f16 per wave per weight set: 9kt*4nt*64lane*8
#define NENC 168
#define NDEC 96

__device__ __forceinline__ float sigm(float x) {
    float e = __builtin_amdgcn_exp2f(-1.4426950408889634f * x);
    return __builtin_amdgcn_rcpf(1.0f + e);
}
__device__ __forceinline__ float tanh_f(float x) {
    float e = __builtin_amdgcn_exp2f(-2.8853900817779268f * x);
    return 2.0f * __builtin_amdgcn_rcpf(1.0f + e) - 1.0f;
}
__device__ __forceinline__ f32x4 mfma(f16x8 a, f16x8 b, f32x4 c) {
    return __builtin_amdgcn_mfma_f32_16x16x32_f16(a, b, c, 0, 0, 0);
}

// ---------- setup kernels ----------

// inputs (B,T,F) f32 -> xf16 [t][b][f] f16
__global__ void k_convert_x(const float* __restrict__ in, _Float16* __restrict__ xf16) {
    int idx = blockIdx.x * 256 + threadIdx.x;     // (t*1024+b)*8+f
    if (idx >= 168 * 1024 * 8) return;
    int f = idx & 7;
    int b = (idx >> 3) & 1023;
    int t = idx >> 13;
    xf16[idx] = (_Float16)in[(b * 168 + t) * 8 + f];
}

// pack weights fragment-linear for the 16-wave tiling:
// flat = wv*18432 + (kt*4 + nt)*512 + lane*8 + j
// n = nt*256 + wv*16 + (lane&15)   (nt == gate index: i,f,g,o)
// k = kt*32 + (lane>>4)*8 + j
__global__ void k_pack_w(const float* __restrict__ Whh, const float* __restrict__ Wih,
                         int IN, _Float16* __restrict__ Wp) {
    int idx = blockIdx.x * 256 + threadIdx.x;
    if (idx >= 294912) return;
    int j    = idx & 7;
    int lane = (idx >> 3) & 63;
    int nt   = (idx >> 9) & 3;
    int kt   = (idx >> 11) % 9;
    int wv   = idx / 18432;
    int n = nt * 256 + wv * 16 + (lane & 15);
    int k = kt * 32 + (lane >> 4) * 8 + j;
    float v = 0.0f;
    if (k < 256)            v = Whh[n * 256 + k];
    else if (k - 256 < IN)  v = Wih[n * IN + (k - 256)];
    Wp[idx] = (_Float16)v;
}

// ---------- main persistent kernel ----------

__global__ __launch_bounds__(1024, 1) void lstm11(
    const _Float16* __restrict__ xf16,
    const _Float16* __restrict__ WpE,
    const _Float16* __restrict__ WpD,
    const float* __restrict__ bihE, const float* __restrict__ bhhE,
    const float* __restrict__ bihD, const float* __restrict__ bhhD,
    const float* __restrict__ fcW, const float* __restrict__ fcb,
    float* __restrict__ out) {

    __shared__ f16x8 Blds[16][8][64];     // 128 KB: kt6,7 (wave-local slices)
    __shared__ f16x8 K8[16][4][16];       //  16 KB: kt8 packed (lanes 0-15)
    __shared__ _Float16 A[16 * 256];      //   8 KB: h tile, 3-bit swizzle
    __shared__ _Float16 xs[16][8];        //  256 B: x staging
    __shared__ float partial[16][16];     //   1 KB: decoder fc partials

    const int tid  = threadIdx.x;
    const int lane = tid & 63;
    const int wv   = tid >> 6;
    const int l15  = lane & 15;
    const int lg   = lane >> 4;
    const int b0   = blockIdx.x * 16;

    const _Float16* wpe = WpE + wv * WPW;
    const _Float16* wpd = WpD + wv * WPW;

    // encoder weights: kt0-4 -> VGPR (20 frags); kt6,7 -> LDS; kt8 -> packed LDS
    f16x8 wr[5][4];
#pragma unroll
    for (int kt = 0; kt < 5; ++kt)
#pragma unroll
        for (int nt = 0; nt < 4; ++nt)
            wr[kt][nt] = *(const f16x8*)(wpe + (size_t)(kt * 4 + nt) * 512 + lane * 8);
#pragma unroll
    for (int kt = 6; kt < 8; ++kt)
#pragma unroll
        for (int nt = 0; nt < 4; ++nt)
            Blds[wv][(kt - 6) * 4 + nt][lane] = *(const f16x8*)(wpe + (size_t)(kt * 4 + nt) * 512 + lane * 8);
    if (lane < 16) {
#pragma unroll
        for (int nt = 0; nt < 4; ++nt)
            K8[wv][nt][lane] = *(const f16x8*)(wpe + (size_t)(8 * 4 + nt) * 512 + lane * 8);
    }

    float bia[4];
#pragma unroll
    for (int nt = 0; nt < 4; ++nt)
        bia[nt] = bihE[nt * 256 + wv * 16 + l15] + bhhE[nt * 256 + wv * 16 + l15];
    const float fcwv = fcW[wv * 16 + l15];
    const float fcbv = fcb[0];

    // swizzled A-frag read offsets: phys = l15*512 + ((blk ^ (l15&7))<<4), blk = kt*4+lg
    int aaddr[8];
#pragma unroll
    for (int kt = 0; kt < 8; ++kt)
        aaddr[kt] = l15 * 512 + ((((kt * 4 + lg) ^ (l15 & 7)) & 31) << 4);

    // zero A (h0 = 0; zeros are swizzle-invariant), load x0
    for (int i = tid; i < 16 * 256; i += 1024) A[i] = (_Float16)0.0f;
    if (tid < 128)
        xs[tid >> 3][tid & 7] = xf16[(size_t)(b0 + (tid >> 3)) * 8 + (tid & 7)];

    float c_st[4] = {0.f, 0.f, 0.f, 0.f};

    __syncthreads();

    // ===================== encoder: 168 steps =====================
#pragma unroll 1
    for (int it = 0; it < NENC; ++it) {
        // stream kt5 (L2-hot, constant address) + x prefetch
        f16x8 s5[4];
#pragma unroll
        for (int nt = 0; nt < 4; ++nt)
            s5[nt] = *(const f16x8*)(wpe + (size_t)(5 * 4 + nt) * 512 + lane * 8);
        _Float16 xreg = (_Float16)0.0f;
        if (it < NENC - 1 && tid < 128)
            xreg = xf16[(size_t)((it + 1) * 1024 + b0 + (tid >> 3)) * 8 + (tid & 7)];

        f32x4 acc[4];
#pragma unroll
        for (int nt = 0; nt < 4; ++nt) { f32x4 v = {bia[nt], bia[nt], bia[nt], bia[nt]}; acc[nt] = v; }

        const char* ab = (const char*)A;
#pragma unroll
        for (int kt = 0; kt < 5; ++kt) {
            f16x8 a = *(const f16x8*)(ab + aaddr[kt]);
#pragma unroll
            for (int nt = 0; nt < 4; ++nt) acc[nt] = mfma(a, wr[kt][nt], acc[nt]);
        }
        {
            f16x8 a = *(const f16x8*)(ab + aaddr[5]);
#pragma unroll
            for (int nt = 0; nt < 4; ++nt) acc[nt] = mfma(a, s5[nt], acc[nt]);
        }
        {
            f16x8 a = *(const f16x8*)(ab + aaddr[6]);
#pragma unroll
            for (int nt = 0; nt < 4; ++nt) acc[nt] = mfma(a, Blds[wv][nt][lane], acc[nt]);
        }
        {
            f16x8 a = *(const f16x8*)(ab + aaddr[7]);
#pragma unroll
            for (int nt = 0; nt < 4; ++nt) acc[nt] = mfma(a, Blds[wv][4 + nt][lane], acc[nt]);
        }
        {
            // kt8: packed B (lanes 0-15 hold the only nonzero k-rows);
            // zero the A-operand on lanes lg>0 instead of masking B.
            f16x8 a = *(const f16x8*)&xs[l15][0];
            _Float16 m = (_Float16)(lg == 0 ? 1.0f : 0.0f);
            a = a * m;
#pragma unroll
            for (int nt = 0; nt < 4; ++nt) acc[nt] = mfma(a, K8[wv][nt][l15], acc[nt]);
        }

        // activation — fully lane-local: gates i,f,g,o = acc[0..3]
        float hnv[4];
#pragma unroll
        for (int r = 0; r < 4; ++r) {
            float cn = sigm(acc[1][r]) * c_st[r] + sigm(acc[0][r]) * tanh_f(acc[2][r]);
            c_st[r] = cn;
            hnv[r] = sigm(acc[3][r]) * tanh_f(cn);
        }

        __syncthreads();   // all reads of A/xs complete
        // write h (swizzled): unit wv*16+l15, rows lg*4+r
#pragma unroll
        for (int r = 0; r < 4; ++r) {
            int row  = lg * 4 + r;
            int colb = (wv * 16 + l15) * 2;
            *(_Float16*)((char*)A + row * 512 + (colb ^ ((row & 7) << 4))) = (_Float16)hnv[r];
        }
        if (it < NENC - 1) {
            if (tid < 128) xs[tid >> 3][tid & 7] = xreg;
        } else {
            // decoder x0 = x167 feat0 (already in xs); zero feats 1..7
            if (tid < 16) {
#pragma unroll
                for (int f = 1; f < 8; ++f) xs[tid][f] = (_Float16)0.0f;
            }
        }
        __syncthreads();
    }

    // ---------- phase switch: decoder weights (all wave-local) ----------
#pragma unroll
    for (int kt = 0; kt < 5; ++kt)
#pragma unroll
        for (int nt = 0; nt < 4; ++nt)
            wr[kt][nt] = *(const f16x8*)(wpd + (size_t)(kt * 4 + nt) * 512 + lane * 8);
#pragma unroll
    for (int kt = 6; kt < 8; ++kt)
#pragma unroll
        for (int nt = 0; nt < 4; ++nt)
            Blds[wv][(kt - 6) * 4 + nt][lane] = *(const f16x8*)(wpd + (size_t)(kt * 4 + nt) * 512 + lane * 8);
    if (lane < 16) {
#pragma unroll
        for (int nt = 0; nt < 4; ++nt)
            K8[wv][nt][lane] = *(const f16x8*)(wpd + (size_t)(8 * 4 + nt) * 512 + lane * 8);
    }
#pragma unroll
    for (int nt = 0; nt < 4; ++nt)
        bia[nt] = bihD[nt * 256 + wv * 16 + l15] + bhhD[nt * 256 + wv * 16 + l15];
    __syncthreads();

    // ===================== decoder: 96 steps (autoregressive) =====================
#pragma unroll 1
    for (int s = 0; s < NDEC; ++s) {
        f16x8 s5[4];
#pragma unroll
        for (int nt = 0; nt < 4; ++nt)
            s5[nt] = *(const f16x8*)(wpd + (size_t)(5 * 4 + nt) * 512 + lane * 8);

        f32x4 acc[4];
#pragma unroll
        for (int nt = 0; nt < 4; ++nt) { f32x4 v = {bia[nt], bia[nt], bia[nt], bia[nt]}; acc[nt] = v; }

        const char* ab = (const char*)A;
#pragma unroll
        for (int kt = 0; kt < 5; ++kt) {
            f16x8 a = *(const f16x8*)(ab + aaddr[kt]);
#pragma unroll
            for (int nt = 0; nt < 4; ++nt) acc[nt] = mfma(a, wr[kt][nt], acc[nt]);
        }
        {
            f16x8 a = *(const f16x8*)(ab + aaddr[5]);
#pragma unroll
            for (int nt = 0; nt < 4; ++nt) acc[nt] = mfma(a, s5[nt], acc[nt]);
        }
        {
            f16x8 a = *(const f16x8*)(ab + aaddr[6]);
#pragma unroll
            for (int nt = 0; nt < 4; ++nt) acc[nt] = mfma(a, Blds[wv][nt][lane], acc[nt]);
        }
        {
            f16x8 a = *(const f16x8*)(ab + aaddr[7]);
#pragma unroll
            for (int nt = 0; nt < 4; ++nt) acc[nt] = mfma(a, Blds[wv][4 + nt][lane], acc[nt]);
        }
        {
            f16x8 a = *(const f16x8*)&xs[l15][0];   // feat0 = pred feedback, rest 0
            _Float16 m = (_Float16)(lg == 0 ? 1.0f : 0.0f);
            a = a * m;
#pragma unroll
            for (int nt = 0; nt < 4; ++nt) acc[nt] = mfma(a, K8[wv][nt][l15], acc[nt]);
        }

        float hnv[4];
#pragma unroll
        for (int r = 0; r < 4; ++r) {
            float cn = sigm(acc[1][r]) * c_st[r] + sigm(acc[0][r]) * tanh_f(acc[2][r]);
            c_st[r] = cn;
            hnv[r] = sigm(acc[3][r]) * tanh_f(cn);
        }
        // fc partial: sum over this wave's 16 units (16-lane shfl groups)
#pragma unroll
        for (int r = 0; r < 4; ++r) {
            float pv = hnv[r] * fcwv;
            pv += __shfl_xor(pv, 1);
            pv += __shfl_xor(pv, 2);
            pv += __shfl_xor(pv, 4);
            pv += __shfl_xor(pv, 8);
            if (l15 == 0) partial[wv][lg * 4 + r] = pv;
        }

        __syncthreads();   // A/xs reads done + partials visible
        // write h (swizzled)
#pragma unroll
        for (int r = 0; r < 4; ++r) {
            int row  = lg * 4 + r;
            int colb = (wv * 16 + l15) * 2;
            *(_Float16*)((char*)A + row * 512 + (colb ^ ((row & 7) << 4))) = (_Float16)hnv[r];
        }
        if (tid < 16) {
            float pr = fcbv;
#pragma unroll
            for (int w = 0; w < 16; ++w) pr += partial[w][tid];
            out[(size_t)(b0 + tid) * 96 + s] = pr;
            xs[tid][0] = (_Float16)pr;        // autoregressive feedback
        }
        __syncthreads();
    }
}

// ---------- launch ----------

extern "C" void kernel_launch(void* const* d_in, const int* in_sizes, int n_in,
                              void* d_out, int out_size, void* d_ws, size_t ws_size,
                              hipStream_t stream) {
    const float* inputs  = (const float*)d_in[0];
    const float* enc_Wih = (const float*)d_in[1];
    const float* enc_Whh = (const float*)d_in[2];
    const float* enc_bih = (const float*)d_in[3];
    const float* enc_bhh = (const float*)d_in[4];
    const float* dec_Wih = (const float*)d_in[5];
    const float* dec_Whh = (const float*)d_in[6];
    const float* dec_bih = (const float*)d_in[7];
    const float* dec_bhh = (const float*)d_in[8];
    const float* fc_W    = (const float*)d_in[9];
    const float* fc_b    = (const float*)d_in[10];

    char* ws = (char*)d_ws;
    _Float16* xf16 = (_Float16*)(ws);                       // 2,752,512 B
    _Float16* WpE  = (_Float16*)(ws + 2752512);             //   589,824 B
    _Float16* WpD  = (_Float16*)(ws + 2752512 + 589824);    //   589,824 B

    k_convert_x<<<dim3(5376), dim3(256), 0, stream>>>(inputs, xf16);
    k_pack_w<<<dim3(1152), dim3(256), 0, stream>>>(enc_Whh, enc_Wih, 8, WpE);
    k_pack_w<<<dim3(1152), dim3(256), 0, stream>>>(dec_Whh, dec_Wih, 1, WpD);

    lstm11<<<dim3(64), dim3(1024), 0, stream>>>(
        xf16, WpE, WpD, enc_bih, enc_bhh, dec_bih, dec_bhh, fc_W, fc_b, (float*)d_out);
}